// Round 5
// baseline (3493.804 us; speedup 1.0000x reference)
//
#include <hip/hip_runtime.h>
#include <hip/hip_bf16.h>
#include <stdint.h>

// MessagePassing segment-sum: out[src[e], k] += edge_attrs_flat[k*E + e]
// E = 4,000,000, F = 16, N = 100,000.
//
// R1: 64M device-scope fp32 atomics -> WRITE_SIZE 2 GB (32 B/atomic): default
//     atomicAdd is device-scope, executed at the memory-side coherence point.
//     3399 us.
// R2: bucket binning -> 1627 us, latency-bound on 4M returning cursor atomics.
// R3/R4: per-XCD L2-side atomics; R3 had a bad nontemporal type, R4 used a
//     nonexistent instruction (global_atomic_pk_add_f32 — pk atomics are
//     f16/bf16 only on gfx950).
// R5: same theory, legal encoding: __hip_atomic_fetch_add with
//     __HIP_MEMORY_SCOPE_WORKGROUP emits global_atomic_add_f32 WITHOUT the
//     system-coherence bit -> executes in the issuing XCD's L2. Correct by
//     construction: 8 per-XCD private output copies (XCD from HW_REG_XCC_ID),
//     so no atomic ever needs cross-XCD coherence. Two feature-half passes
//     keep each copy at 3.2 MB/XCD (< 4 MiB L2). Final gather sums 16 copies.

#define F_FEATS 16

typedef float f4 __attribute__((ext_vector_type(4)));
typedef int   i4 __attribute__((ext_vector_type(4)));

__device__ __forceinline__ uint32_t xcd_id() {
    uint32_t x;
    asm volatile("s_getreg_b32 %0, hwreg(HW_REG_XCC_ID)" : "=s"(x));
    return x & 7u;
}

// L2-side (XCD-local) fp32 atomic add, no returned value.
__device__ __forceinline__ void l2_atomic_add(float* p, float v) {
    (void)__hip_atomic_fetch_add(p, v, __ATOMIC_RELAXED,
                                 __HIP_MEMORY_SCOPE_WORKGROUP);
}

// One feature-half pass: each thread handles 4 consecutive edges x 8 feats.
__global__ __launch_bounds__(256) void mp_xcd_pass(
    const float* __restrict__ vals,   // (F, E) view of edge_attrs
    const int*   __restrict__ src,    // attr_idx row 0
    float*       __restrict__ copies, // [8 xcd][N][8] for this half
    int E, int N, int k0)
{
    long long t = (long long)blockIdx.x * 256 + threadIdx.x;
    long long e = t * 4;
    if (e >= E) return;

    i4 s = __builtin_nontemporal_load((const i4*)(src + e));
    f4 v[8];
#pragma unroll
    for (int j = 0; j < 8; ++j)
        v[j] = __builtin_nontemporal_load(
            (const f4*)(vals + (size_t)(k0 + j) * E + e));

    float* cp = copies + (size_t)xcd_id() * N * 8;
#pragma unroll
    for (int i = 0; i < 4; ++i) {
        float* b = cp + (size_t)s[i] * 8;   // 32 B node row in this half
#pragma unroll
        for (int j = 0; j < 8; ++j)
            l2_atomic_add(b + j, v[j][i]);
    }
}

// out[n*16 + k] = sum over 8 XCD copies of half (k>>3), feature (k&7).
__global__ __launch_bounds__(256) void mp_gather(
    const float* __restrict__ buf,    // [2 half][8 xcd][N][8]
    float* __restrict__ out, int N)
{
    int t = blockIdx.x * 256 + threadIdx.x;
    if (t >= N * F_FEATS) return;
    int n = t >> 4, k = t & 15, h = k >> 3, k7 = k & 7;
    const float* p = buf + ((size_t)h * 8 * N + (size_t)n) * 8 + k7;
    float acc = 0.f;
#pragma unroll
    for (int x = 0; x < 8; ++x)
        acc += p[(size_t)x * N * 8];
    out[t] = acc;
}

// ---------------- Fallback (R1): direct fp32 atomics ----------------
__global__ __launch_bounds__(256) void mp_scatter_fallback(
    const float* __restrict__ vals, const int* __restrict__ src,
    float* __restrict__ out, long long E)
{
    long long e = ((long long)blockIdx.x * blockDim.x + threadIdx.x) * 4;
    if (e >= E) return;
    i4 s = *reinterpret_cast<const i4*>(src + e);
    long long b0 = (long long)s[0] * F_FEATS, b1 = (long long)s[1] * F_FEATS;
    long long b2 = (long long)s[2] * F_FEATS, b3 = (long long)s[3] * F_FEATS;
#pragma unroll
    for (int k = 0; k < F_FEATS; ++k) {
        f4 v = *reinterpret_cast<const f4*>(vals + (long long)k * E + e);
        atomicAdd(out + b0 + k, v[0]);
        atomicAdd(out + b1 + k, v[1]);
        atomicAdd(out + b2 + k, v[2]);
        atomicAdd(out + b3 + k, v[3]);
    }
}

extern "C" void kernel_launch(void* const* d_in, const int* in_sizes, int n_in,
                              void* d_out, int out_size, void* d_ws, size_t ws_size,
                              hipStream_t stream) {
    const float* edge_attrs = (const float*)d_in[0];   // (E, F) buffer
    const int*   attr_idx   = (const int*)d_in[1];     // 2*E; row 0 = src
    int E = in_sizes[1] / 2;                           // 4,000,000
    int N = out_size / F_FEATS;                        // 100,000

    // 2 halves x 8 XCDs x N x 8 feats x 4 B = 51.2 MB
    size_t half_bytes = (size_t)8 * N * 8 * sizeof(float);
    size_t need = 2 * half_bytes;

    if (ws_size >= need) {
        float* buf = (float*)d_ws;
        (void)hipMemsetAsync(buf, 0, need, stream);

        int gridP = (E / 4 + 255) / 256;               // 3907
        // Pass 0: features 0..7 -> buf[0]; Pass 1: features 8..15 -> buf[1].
        mp_xcd_pass<<<gridP, 256, 0, stream>>>(
            edge_attrs, attr_idx, buf, E, N, 0);
        mp_xcd_pass<<<gridP, 256, 0, stream>>>(
            edge_attrs, attr_idx, buf + half_bytes / sizeof(float), E, N, 8);

        int gridG = (N * F_FEATS + 255) / 256;         // 6250
        mp_gather<<<gridG, 256, 0, stream>>>(buf, (float*)d_out, N);
    } else {
        (void)hipMemsetAsync(d_out, 0, (size_t)out_size * sizeof(float), stream);
        long long threads = ((long long)E + 3) / 4;
        long long grid = (threads + 255) / 256;
        mp_scatter_fallback<<<(dim3)(unsigned)grid, 256, 0, stream>>>(
            edge_attrs, attr_idx, (float*)d_out, E);
    }
}